// Round 4
// baseline (622.154 us; speedup 1.0000x reference)
//
#include <hip/hip_runtime.h>
#include <hip/hip_bf16.h>

// ---------------------------------------------------------------------------
// GNN: h = relu(GCN(x)); h = relu(GAT(h)); h = relu(GCN(h)); h = relu(GAT(h));
//      z = h @ Wo + bo.  Outputs: [h (N*128), z (N*64)] fp32.
// R4: dwordx4 half-wave gather kept, but remainder loop made divergence-free
//     (no clamped/predicated shfl: invalid lanes hold wgt=0, sid=0 and are
//     read directly). GAT weights reverted to R2's proven online-softmax.
// ---------------------------------------------------------------------------

#define WAVE 64

// ------------------------------ graph build --------------------------------

__global__ void k_zero_i32(int* __restrict__ p, int n) {
    int i = blockIdx.x * 256 + threadIdx.x;
    if (i < n) p[i] = 0;
}

__global__ void k_hist(const int* __restrict__ ei, int* __restrict__ deg,
                       int E, int Et) {
    int e = blockIdx.x * 256 + threadIdx.x;
    if (e >= Et) return;
    int d = (e < E) ? ei[E + e] : (e - E);
    atomicAdd(&deg[d], 1);
}

__global__ void k_scan1(const int* __restrict__ deg, int* __restrict__ bs, int n) {
    __shared__ int tmp[256];
    int tid = threadIdx.x;
    int gid = blockIdx.x * 256 + tid;
    tmp[tid] = (gid < n) ? deg[gid] : 0;
    __syncthreads();
    for (int off = 128; off > 0; off >>= 1) {
        if (tid < off) tmp[tid] += tmp[tid + off];
        __syncthreads();
    }
    if (tid == 0) bs[blockIdx.x] = tmp[0];
}

__global__ void k_scan2(int* __restrict__ bs, int nb) {
    __shared__ int tmp[256];
    int tid = threadIdx.x;
    int v = (tid < nb) ? bs[tid] : 0;
    tmp[tid] = v;
    __syncthreads();
    for (int off = 1; off < 256; off <<= 1) {
        int t = (tid >= off) ? tmp[tid - off] : 0;
        __syncthreads();
        tmp[tid] += t;
        __syncthreads();
    }
    if (tid < nb) bs[tid] = tmp[tid] - v;   // exclusive
}

__global__ void k_scan3(const int* __restrict__ deg, const int* __restrict__ bs,
                        int* __restrict__ rowp, int* __restrict__ cur,
                        float* __restrict__ inv, int n, int total) {
    __shared__ int tmp[256];
    int tid = threadIdx.x;
    int gid = blockIdx.x * 256 + tid;
    int v = (gid < n) ? deg[gid] : 0;
    tmp[tid] = v;
    __syncthreads();
    for (int off = 1; off < 256; off <<= 1) {
        int t = (tid >= off) ? tmp[tid - off] : 0;
        __syncthreads();
        tmp[tid] += t;
        __syncthreads();
    }
    if (gid < n) {
        int rp = bs[blockIdx.x] + tmp[tid] - v;
        rowp[gid] = rp;
        cur[gid] = rp;
        inv[gid] = rsqrtf((float)v);
    }
    if (gid == 0) rowp[n] = total;
}

__global__ void k_scatter(const int* __restrict__ ei, int* __restrict__ cur,
                          int* __restrict__ esrc, int E, int Et) {
    int e = blockIdx.x * 256 + threadIdx.x;
    if (e >= Et) return;
    int s, d;
    if (e < E) { s = ei[e]; d = ei[E + e]; }
    else       { s = d = e - E; }
    int pos = atomicAdd(&cur[d], 1);
    esrc[pos] = s;
}

// ------------------------------ GEMM (fp32) --------------------------------

template <int NC>
__global__ __launch_bounds__(256) void gemm_k128(
    const float* __restrict__ A, const float* __restrict__ W,
    const float* __restrict__ bias, float* __restrict__ out,
    int M, int do_relu) {
    constexpr int TR = 4096 / NC;
    constexpr int CG = NC / 4;
    constexpr int AP = 132;
    __shared__ float Ws[64 * NC];
    __shared__ float As[TR * AP];

    const int tid = threadIdx.x;
    const int cg = tid % CG;
    const int rg = tid / CG;
    const int row0 = blockIdx.x * TR;

    for (int i = tid; i < TR * 32; i += 256) {
        int r = i >> 5, c4 = i & 31;
        int gr = row0 + r;
        float4 v = make_float4(0.f, 0.f, 0.f, 0.f);
        if (gr < M) v = ((const float4*)A)[(size_t)gr * 32 + c4];
        *((float4*)(As + r * AP + c4 * 4)) = v;
    }

    float acc[4][4] = {{0.f}};
    for (int half = 0; half < 2; ++half) {
        __syncthreads();
        for (int i = tid; i < 64 * NC / 4; i += 256)
            ((float4*)Ws)[i] = ((const float4*)W)[half * (64 * NC / 4) + i];
        __syncthreads();
#pragma unroll
        for (int k4 = 0; k4 < 16; ++k4) {
            float4 aa[4];
#pragma unroll
            for (int i = 0; i < 4; ++i)
                aa[i] = *((const float4*)(As + (rg * 4 + i) * AP + half * 64 + k4 * 4));
#pragma unroll
            for (int kk = 0; kk < 4; ++kk) {
                float4 w = ((const float4*)Ws)[(k4 * 4 + kk) * CG + cg];
#pragma unroll
                for (int i = 0; i < 4; ++i) {
                    float av = ((const float*)&aa[i])[kk];
                    acc[i][0] = fmaf(av, w.x, acc[i][0]);
                    acc[i][1] = fmaf(av, w.y, acc[i][1]);
                    acc[i][2] = fmaf(av, w.z, acc[i][2]);
                    acc[i][3] = fmaf(av, w.w, acc[i][3]);
                }
            }
        }
    }

    float4 b4 = make_float4(0.f, 0.f, 0.f, 0.f);
    if (bias) b4 = ((const float4*)bias)[cg];
#pragma unroll
    for (int i = 0; i < 4; ++i) {
        int gr = row0 + rg * 4 + i;
        if (gr < M) {
            float4 r;
            r.x = acc[i][0] + b4.x;
            r.y = acc[i][1] + b4.y;
            r.z = acc[i][2] + b4.z;
            r.w = acc[i][3] + b4.w;
            if (do_relu) {
                r.x = fmaxf(r.x, 0.f); r.y = fmaxf(r.y, 0.f);
                r.z = fmaxf(r.z, 0.f); r.w = fmaxf(r.w, 0.f);
            }
            ((float4*)out)[(size_t)gr * CG + cg] = r;
        }
    }
}

// --------------------------- aggregation kernels ---------------------------
// One wave per destination node. lane = 32*h + q: half-wave h handles edge
// j+h of each pair, lane owns features 4q..4q+3. One dwordx4 per 2 edges.
// INVARIANT required by gather_accum4: every lane (including those past cnt)
// holds wgt == 0 if its index >= cnt, and a sid that is a valid row (0 ok).
// All 64 lanes must be active (uniform control flow).

__device__ __forceinline__ void gather_accum4(
    const float* __restrict__ xw, int q, int h, int cnt, int sid, float wgt,
    float acc[4]) {
    int j = 0;
    for (; j + 16 <= cnt; j += 16) {
        float4 x[8];
        float w[8];
#pragma unroll
        for (int u = 0; u < 8; ++u) {
            int idx = j + 2 * u + h;
            int s = __shfl(sid, idx);
            w[u] = __shfl(wgt, idx);
            x[u] = *(const float4*)(xw + (size_t)s * 128 + q * 4);
        }
#pragma unroll
        for (int u = 0; u < 8; ++u) {
            acc[0] = fmaf(w[u], x[u].x, acc[0]);
            acc[1] = fmaf(w[u], x[u].y, acc[1]);
            acc[2] = fmaf(w[u], x[u].z, acc[2]);
            acc[3] = fmaf(w[u], x[u].w, acc[3]);
        }
    }
    // tail: no clamp, no divergence. idx = j+h <= cnt <= 63 here (a cnt of 64
    // is fully consumed by the main loop), and lane idx>=cnt holds wgt=0.
    for (; j < cnt; j += 2) {
        int idx = j + h;
        int s = __shfl(sid, idx);
        float wj = __shfl(wgt, idx);
        float4 xv = *(const float4*)(xw + (size_t)s * 128 + q * 4);
        acc[0] = fmaf(wj, xv.x, acc[0]);
        acc[1] = fmaf(wj, xv.y, acc[1]);
        acc[2] = fmaf(wj, xv.z, acc[2]);
        acc[3] = fmaf(wj, xv.w, acc[3]);
    }
}

__device__ __forceinline__ void finish_store(
    float acc[4], const float* __restrict__ bias, float* __restrict__ out,
    int n, int q, int h) {
#pragma unroll
    for (int i = 0; i < 4; ++i) acc[i] += __shfl_xor(acc[i], 32);
    if (h == 0) {
        float4 b = ((const float4*)bias)[q];
        float4 r;
        r.x = fmaxf(acc[0] + b.x, 0.f);
        r.y = fmaxf(acc[1] + b.y, 0.f);
        r.z = fmaxf(acc[2] + b.z, 0.f);
        r.w = fmaxf(acc[3] + b.w, 0.f);
        ((float4*)(out + (size_t)n * 128))[q] = r;
    }
}

__global__ __launch_bounds__(256) void k_gcn_agg(
    const float* __restrict__ xw, const int* __restrict__ rowp,
    const int* __restrict__ esrc, const float* __restrict__ inv,
    const float* __restrict__ bias, float* __restrict__ out, int Nn) {
    int gid = blockIdx.x * 256 + threadIdx.x;
    int n = gid >> 6, lane = gid & 63;
    if (n >= Nn) return;
    int q = lane & 31, h = lane >> 5;
    int beg = rowp[n], end = rowp[n + 1];
    float invd = inv[n];
    float acc[4] = {0.f, 0.f, 0.f, 0.f};
    for (int base = beg; base < end; base += WAVE) {
        int e = base + lane;
        bool valid = (e < end);
        int sid = valid ? esrc[e] : 0;
        float c = valid ? invd * inv[sid] : 0.f;
        gather_accum4(xw, q, h, min(WAVE, end - base), sid, c, acc);
    }
    finish_store(acc, bias, out, n, q, h);
}

__global__ __launch_bounds__(256) void k_alpha(
    const float* __restrict__ xw, const float* __restrict__ asrc,
    const float* __restrict__ adst, float* __restrict__ s_out,
    float* __restrict__ d_out_, int Nn) {
    int gid = blockIdx.x * 256 + threadIdx.x;
    int n = gid >> 6, lane = gid & 63;
    if (n >= Nn) return;
    float2 xv = *(const float2*)(xw + (size_t)n * 128 + lane * 2);
    float2 sa = ((const float2*)asrc)[lane];
    float2 da = ((const float2*)adst)[lane];
    float s = fmaf(xv.y, sa.y, xv.x * sa.x);
    float d = fmaf(xv.y, da.y, xv.x * da.x);
#pragma unroll
    for (int off = 32; off > 0; off >>= 1) {
        s += __shfl_xor(s, off);
        d += __shfl_xor(d, off);
    }
    if (lane == 0) { s_out[n] = s; d_out_[n] = d; }
}

__global__ __launch_bounds__(256) void k_gat_agg(
    const float* __restrict__ xw, const int* __restrict__ rowp,
    const int* __restrict__ esrc, const float* __restrict__ as_,
    const float* __restrict__ ad_, const float* __restrict__ bias,
    float* __restrict__ out, int Nn) {
    int gid = blockIdx.x * 256 + threadIdx.x;
    int n = gid >> 6, lane = gid & 63;
    if (n >= Nn) return;
    int q = lane & 31, h = lane >> 5;
    int beg = rowp[n], end = rowp[n + 1];
    float adn = ad_[n];

    // online softmax over edges (R2-proven code path)
    float m = -1e30f, ssum = 0.f;
    for (int e = beg + lane; e < end; e += WAVE) {
        float v = as_[esrc[e]] + adn;
        v = (v > 0.f) ? v : 0.2f * v;
        float mn = fmaxf(m, v);
        ssum = ssum * __expf(m - mn) + __expf(v - mn);
        m = mn;
    }
#pragma unroll
    for (int off = 32; off > 0; off >>= 1) {
        float mo = __shfl_xor(m, off);
        float so = __shfl_xor(ssum, off);
        float mn = fmaxf(m, mo);
        ssum = ssum * __expf(m - mn) + so * __expf(mo - mn);
        m = mn;
    }
    float rden = 1.f / ssum;

    // weighted aggregation (recompute logits; as_ is L2-resident)
    float acc[4] = {0.f, 0.f, 0.f, 0.f};
    for (int base = beg; base < end; base += WAVE) {
        int e = base + lane;
        bool valid = (e < end);
        int sid = valid ? esrc[e] : 0;
        float wgt = 0.f;
        if (valid) {
            float v = as_[sid] + adn;
            v = (v > 0.f) ? v : 0.2f * v;
            wgt = __expf(v - m) * rden;
        }
        gather_accum4(xw, q, h, min(WAVE, end - base), sid, wgt, acc);
    }
    finish_store(acc, bias, out, n, q, h);
}

// ------------------------------- launch ------------------------------------

extern "C" void kernel_launch(void* const* d_in, const int* in_sizes, int n_in,
                              void* d_out, int out_size, void* d_ws, size_t ws_size,
                              hipStream_t stream) {
    const float* x   = (const float*)d_in[0];
    const int*   ei  = (const int*)d_in[1];
    const float* W1  = (const float*)d_in[2];
    const float* b1  = (const float*)d_in[3];
    const float* Wg1 = (const float*)d_in[4];
    const float* as1 = (const float*)d_in[5];
    const float* ad1 = (const float*)d_in[6];
    const float* bg1 = (const float*)d_in[7];
    const float* W2  = (const float*)d_in[8];
    const float* b2  = (const float*)d_in[9];
    const float* Wg2 = (const float*)d_in[10];
    const float* as2 = (const float*)d_in[11];
    const float* ad2 = (const float*)d_in[12];
    const float* bg2 = (const float*)d_in[13];
    const float* Wo  = (const float*)d_in[14];
    const float* bo  = (const float*)d_in[15];

    const int Nn = in_sizes[0] / 128;
    const int E  = in_sizes[1] / 2;
    const int Et = E + Nn;
    const int H  = 128;

    float* outH = (float*)d_out;
    float* outZ = outH + (size_t)Nn * H;

    char* p = (char*)d_ws;
    auto carve = [&](size_t bytes) {
        char* r = p;
        p += (bytes + 255) & ~(size_t)255;
        return r;
    };
    float* bufA  = (float*)carve((size_t)Nn * H * sizeof(float));
    float* alS   = (float*)carve((size_t)Nn * sizeof(float));
    float* alD   = (float*)carve((size_t)Nn * sizeof(float));
    float* inv   = (float*)carve((size_t)Nn * sizeof(float));
    int*   deg   = (int*)carve((size_t)Nn * sizeof(int));
    int*   rowp  = (int*)carve((size_t)(Nn + 1) * sizeof(int));
    int*   cur   = (int*)carve((size_t)Nn * sizeof(int));
    int*   bsums = (int*)carve(256 * sizeof(int));
    int*   esrc  = (int*)carve((size_t)Et * sizeof(int));
    (void)ws_size; (void)n_in; (void)out_size;

    const int nb = (Nn + 255) / 256;
    const int ebk = (Et + 255) / 256;
    const int aggBlocks = (Nn * WAVE + 255) / 256;
    const int gemmB128 = (Nn + 31) / 32;
    const int gemmB64  = (Nn + 63) / 64;

    k_zero_i32<<<nb, 256, 0, stream>>>(deg, Nn);
    k_hist<<<ebk, 256, 0, stream>>>(ei, deg, E, Et);
    k_scan1<<<nb, 256, 0, stream>>>(deg, bsums, Nn);
    k_scan2<<<1, 256, 0, stream>>>(bsums, nb);
    k_scan3<<<nb, 256, 0, stream>>>(deg, bsums, rowp, cur, inv, Nn, Et);
    k_scatter<<<ebk, 256, 0, stream>>>(ei, cur, esrc, E, Et);

    gemm_k128<128><<<gemmB128, 256, 0, stream>>>(x, W1, nullptr, bufA, Nn, 0);
    k_gcn_agg<<<aggBlocks, 256, 0, stream>>>(bufA, rowp, esrc, inv, b1, outH, Nn);

    gemm_k128<128><<<gemmB128, 256, 0, stream>>>(outH, Wg1, nullptr, bufA, Nn, 0);
    k_alpha<<<aggBlocks, 256, 0, stream>>>(bufA, as1, ad1, alS, alD, Nn);
    k_gat_agg<<<aggBlocks, 256, 0, stream>>>(bufA, rowp, esrc, alS, alD, bg1, outH, Nn);

    gemm_k128<128><<<gemmB128, 256, 0, stream>>>(outH, W2, nullptr, bufA, Nn, 0);
    k_gcn_agg<<<aggBlocks, 256, 0, stream>>>(bufA, rowp, esrc, inv, b2, outH, Nn);

    gemm_k128<128><<<gemmB128, 256, 0, stream>>>(outH, Wg2, nullptr, bufA, Nn, 0);
    k_alpha<<<aggBlocks, 256, 0, stream>>>(bufA, as2, ad2, alS, alD, Nn);
    k_gat_agg<<<aggBlocks, 256, 0, stream>>>(bufA, rowp, esrc, alS, alD, bg2, outH, Nn);

    gemm_k128<64><<<gemmB64, 256, 0, stream>>>(outH, Wo, bo, outZ, Nn, 0);
}

// Round 5
// 563.219 us; speedup vs baseline: 1.1046x; 1.1046x over previous
//
#include <hip/hip_runtime.h>
#include <hip/hip_bf16.h>
#include <hip/hip_fp16.h>

// ---------------------------------------------------------------------------
// GNN: h = relu(GCN(x)); h = relu(GAT(h)); h = relu(GCN(h)); h = relu(GAT(h));
//      z = h @ Wo + bo.  Outputs: [h (N*128), z (N*64)] fp32.
// R5: xw (GEMM output, gather payload) stored in FP16 -> gather bytes halve
//     (the agg kernels are pinned at ~3.5 TB/s on the L2-miss path, so bytes
//     are the only lever). Quarter-wave gather: 16 lanes x dwordx4 = one
//     256 B fp16 row; 4 edges per step, 8-deep pipeline. All accumulation
//     and h remain fp32.
// ---------------------------------------------------------------------------

#define WAVE 64

// ------------------------------ graph build --------------------------------

__global__ void k_zero_i32(int* __restrict__ p, int n) {
    int i = blockIdx.x * 256 + threadIdx.x;
    if (i < n) p[i] = 0;
}

__global__ void k_hist(const int* __restrict__ ei, int* __restrict__ deg,
                       int E, int Et) {
    int e = blockIdx.x * 256 + threadIdx.x;
    if (e >= Et) return;
    int d = (e < E) ? ei[E + e] : (e - E);
    atomicAdd(&deg[d], 1);
}

__global__ void k_scan1(const int* __restrict__ deg, int* __restrict__ bs, int n) {
    __shared__ int tmp[256];
    int tid = threadIdx.x;
    int gid = blockIdx.x * 256 + tid;
    tmp[tid] = (gid < n) ? deg[gid] : 0;
    __syncthreads();
    for (int off = 128; off > 0; off >>= 1) {
        if (tid < off) tmp[tid] += tmp[tid + off];
        __syncthreads();
    }
    if (tid == 0) bs[blockIdx.x] = tmp[0];
}

__global__ void k_scan2(int* __restrict__ bs, int nb) {
    __shared__ int tmp[256];
    int tid = threadIdx.x;
    int v = (tid < nb) ? bs[tid] : 0;
    tmp[tid] = v;
    __syncthreads();
    for (int off = 1; off < 256; off <<= 1) {
        int t = (tid >= off) ? tmp[tid - off] : 0;
        __syncthreads();
        tmp[tid] += t;
        __syncthreads();
    }
    if (tid < nb) bs[tid] = tmp[tid] - v;   // exclusive
}

__global__ void k_scan3(const int* __restrict__ deg, const int* __restrict__ bs,
                        int* __restrict__ rowp, int* __restrict__ cur,
                        float* __restrict__ inv, int n, int total) {
    __shared__ int tmp[256];
    int tid = threadIdx.x;
    int gid = blockIdx.x * 256 + tid;
    int v = (gid < n) ? deg[gid] : 0;
    tmp[tid] = v;
    __syncthreads();
    for (int off = 1; off < 256; off <<= 1) {
        int t = (tid >= off) ? tmp[tid - off] : 0;
        __syncthreads();
        tmp[tid] += t;
        __syncthreads();
    }
    if (gid < n) {
        int rp = bs[blockIdx.x] + tmp[tid] - v;
        rowp[gid] = rp;
        cur[gid] = rp;
        inv[gid] = rsqrtf((float)v);
    }
    if (gid == 0) rowp[n] = total;
}

__global__ void k_scatter(const int* __restrict__ ei, int* __restrict__ cur,
                          int* __restrict__ esrc, int E, int Et) {
    int e = blockIdx.x * 256 + threadIdx.x;
    if (e >= Et) return;
    int s, d;
    if (e < E) { s = ei[e]; d = ei[E + e]; }
    else       { s = d = e - E; }
    int pos = atomicAdd(&cur[d], 1);
    esrc[pos] = s;
}

// ------------------------------ GEMM (fp32 in, fp32/fp16 out) --------------

template <int NC, typename OT>
__global__ __launch_bounds__(256) void gemm_k128(
    const float* __restrict__ A, const float* __restrict__ W,
    const float* __restrict__ bias, OT* __restrict__ out,
    int M, int do_relu) {
    constexpr int TR = 4096 / NC;
    constexpr int CG = NC / 4;
    constexpr int AP = 132;
    __shared__ float Ws[64 * NC];
    __shared__ float As[TR * AP];

    const int tid = threadIdx.x;
    const int cg = tid % CG;
    const int rg = tid / CG;
    const int row0 = blockIdx.x * TR;

    for (int i = tid; i < TR * 32; i += 256) {
        int r = i >> 5, c4 = i & 31;
        int gr = row0 + r;
        float4 v = make_float4(0.f, 0.f, 0.f, 0.f);
        if (gr < M) v = ((const float4*)A)[(size_t)gr * 32 + c4];
        *((float4*)(As + r * AP + c4 * 4)) = v;
    }

    float acc[4][4] = {{0.f}};
    for (int half = 0; half < 2; ++half) {
        __syncthreads();
        for (int i = tid; i < 64 * NC / 4; i += 256)
            ((float4*)Ws)[i] = ((const float4*)W)[half * (64 * NC / 4) + i];
        __syncthreads();
#pragma unroll
        for (int k4 = 0; k4 < 16; ++k4) {
            float4 aa[4];
#pragma unroll
            for (int i = 0; i < 4; ++i)
                aa[i] = *((const float4*)(As + (rg * 4 + i) * AP + half * 64 + k4 * 4));
#pragma unroll
            for (int kk = 0; kk < 4; ++kk) {
                float4 w = ((const float4*)Ws)[(k4 * 4 + kk) * CG + cg];
#pragma unroll
                for (int i = 0; i < 4; ++i) {
                    float av = ((const float*)&aa[i])[kk];
                    acc[i][0] = fmaf(av, w.x, acc[i][0]);
                    acc[i][1] = fmaf(av, w.y, acc[i][1]);
                    acc[i][2] = fmaf(av, w.z, acc[i][2]);
                    acc[i][3] = fmaf(av, w.w, acc[i][3]);
                }
            }
        }
    }

    float4 b4 = make_float4(0.f, 0.f, 0.f, 0.f);
    if (bias) b4 = ((const float4*)bias)[cg];
#pragma unroll
    for (int i = 0; i < 4; ++i) {
        int gr = row0 + rg * 4 + i;
        if (gr < M) {
            float rx = acc[i][0] + b4.x;
            float ry = acc[i][1] + b4.y;
            float rz = acc[i][2] + b4.z;
            float rw = acc[i][3] + b4.w;
            if (do_relu) {
                rx = fmaxf(rx, 0.f); ry = fmaxf(ry, 0.f);
                rz = fmaxf(rz, 0.f); rw = fmaxf(rw, 0.f);
            }
            if constexpr (sizeof(OT) == 2) {
                __half2* orow = (__half2*)((__half*)out + (size_t)gr * NC);
                orow[cg * 2]     = __floats2half2_rn(rx, ry);
                orow[cg * 2 + 1] = __floats2half2_rn(rz, rw);
            } else {
                ((float4*)out)[(size_t)gr * CG + cg] =
                    make_float4(rx, ry, rz, rw);
            }
        }
    }
}

// --------------------------- aggregation kernels ---------------------------
// One wave per destination node. lane = 16*g + q: quarter-wave g handles edge
// j+g of each group of 4; lane owns fp16 features 8q..8q+7 (16 B dwordx4).
// INVARIANT: lanes with index >= cnt hold wgt == 0 and a valid sid (0 ok);
// all 64 lanes active (uniform control flow). Tail idx = j+g stays <= 63
// (tail j is a multiple of 4, <= 60).

__device__ __forceinline__ void gather_accum_h(
    const __half* __restrict__ xw, int q, int g, int cnt, int sid, float wgt,
    float acc[8]) {
    int j = 0;
    for (; j + 32 <= cnt; j += 32) {
        float4 x[8];
        float w[8];
#pragma unroll
        for (int u = 0; u < 8; ++u) {
            int idx = j + 4 * u + g;
            int s = __shfl(sid, idx);
            w[u] = __shfl(wgt, idx);
            x[u] = *(const float4*)(xw + (size_t)s * 128 + q * 8);
        }
#pragma unroll
        for (int u = 0; u < 8; ++u) {
            const __half2* h2 = (const __half2*)&x[u];
#pragma unroll
            for (int i = 0; i < 4; ++i) {
                float2 c = __half22float2(h2[i]);
                acc[2 * i]     = fmaf(w[u], c.x, acc[2 * i]);
                acc[2 * i + 1] = fmaf(w[u], c.y, acc[2 * i + 1]);
            }
        }
    }
    for (; j < cnt; j += 4) {
        int idx = j + g;
        int s = __shfl(sid, idx);
        float wj = __shfl(wgt, idx);
        float4 xv = *(const float4*)(xw + (size_t)s * 128 + q * 8);
        const __half2* h2 = (const __half2*)&xv;
#pragma unroll
        for (int i = 0; i < 4; ++i) {
            float2 c = __half22float2(h2[i]);
            acc[2 * i]     = fmaf(wj, c.x, acc[2 * i]);
            acc[2 * i + 1] = fmaf(wj, c.y, acc[2 * i + 1]);
        }
    }
}

__device__ __forceinline__ void finish_store_q(
    float acc[8], const float* __restrict__ bias, float* __restrict__ out,
    int n, int q, int g) {
#pragma unroll
    for (int i = 0; i < 8; ++i) {
        acc[i] += __shfl_xor(acc[i], 16);
        acc[i] += __shfl_xor(acc[i], 32);
    }
    if (g == 0) {
        float4 b0 = ((const float4*)bias)[q * 2];
        float4 b1 = ((const float4*)bias)[q * 2 + 1];
        float4 r0, r1;
        r0.x = fmaxf(acc[0] + b0.x, 0.f);
        r0.y = fmaxf(acc[1] + b0.y, 0.f);
        r0.z = fmaxf(acc[2] + b0.z, 0.f);
        r0.w = fmaxf(acc[3] + b0.w, 0.f);
        r1.x = fmaxf(acc[4] + b1.x, 0.f);
        r1.y = fmaxf(acc[5] + b1.y, 0.f);
        r1.z = fmaxf(acc[6] + b1.z, 0.f);
        r1.w = fmaxf(acc[7] + b1.w, 0.f);
        float4* orow = (float4*)(out + (size_t)n * 128);
        orow[q * 2]     = r0;
        orow[q * 2 + 1] = r1;
    }
}

__global__ __launch_bounds__(256) void k_gcn_agg(
    const __half* __restrict__ xw, const int* __restrict__ rowp,
    const int* __restrict__ esrc, const float* __restrict__ inv,
    const float* __restrict__ bias, float* __restrict__ out, int Nn) {
    int gid = blockIdx.x * 256 + threadIdx.x;
    int n = gid >> 6, lane = gid & 63;
    if (n >= Nn) return;
    int q = lane & 15, g = lane >> 4;
    int beg = rowp[n], end = rowp[n + 1];
    float invd = inv[n];
    float acc[8] = {0.f, 0.f, 0.f, 0.f, 0.f, 0.f, 0.f, 0.f};
    for (int base = beg; base < end; base += WAVE) {
        int e = base + lane;
        bool valid = (e < end);
        int sid = valid ? esrc[e] : 0;
        float c = valid ? invd * inv[sid] : 0.f;
        gather_accum_h(xw, q, g, min(WAVE, end - base), sid, c, acc);
    }
    finish_store_q(acc, bias, out, n, q, g);
}

__global__ __launch_bounds__(256) void k_alpha(
    const __half* __restrict__ xw, const float* __restrict__ asrc,
    const float* __restrict__ adst, float* __restrict__ s_out,
    float* __restrict__ d_out_, int Nn) {
    int gid = blockIdx.x * 256 + threadIdx.x;
    int n = gid >> 6, lane = gid & 63;
    if (n >= Nn) return;
    float2 xv = __half22float2(*(const __half2*)(xw + (size_t)n * 128 + lane * 2));
    float2 sa = ((const float2*)asrc)[lane];
    float2 da = ((const float2*)adst)[lane];
    float s = fmaf(xv.y, sa.y, xv.x * sa.x);
    float d = fmaf(xv.y, da.y, xv.x * da.x);
#pragma unroll
    for (int off = 32; off > 0; off >>= 1) {
        s += __shfl_xor(s, off);
        d += __shfl_xor(d, off);
    }
    if (lane == 0) { s_out[n] = s; d_out_[n] = d; }
}

__global__ __launch_bounds__(256) void k_gat_agg(
    const __half* __restrict__ xw, const int* __restrict__ rowp,
    const int* __restrict__ esrc, const float* __restrict__ as_,
    const float* __restrict__ ad_, const float* __restrict__ bias,
    float* __restrict__ out, int Nn) {
    int gid = blockIdx.x * 256 + threadIdx.x;
    int n = gid >> 6, lane = gid & 63;
    if (n >= Nn) return;
    int q = lane & 15, g = lane >> 4;
    int beg = rowp[n], end = rowp[n + 1];
    float adn = ad_[n];

    // online softmax over edges (R2-proven code path)
    float m = -1e30f, ssum = 0.f;
    for (int e = beg + lane; e < end; e += WAVE) {
        float v = as_[esrc[e]] + adn;
        v = (v > 0.f) ? v : 0.2f * v;
        float mn = fmaxf(m, v);
        ssum = ssum * __expf(m - mn) + __expf(v - mn);
        m = mn;
    }
#pragma unroll
    for (int off = 32; off > 0; off >>= 1) {
        float mo = __shfl_xor(m, off);
        float so = __shfl_xor(ssum, off);
        float mn = fmaxf(m, mo);
        ssum = ssum * __expf(m - mn) + so * __expf(mo - mn);
        m = mn;
    }
    float rden = 1.f / ssum;

    // weighted aggregation (recompute logits; as_ is cache-resident)
    float acc[8] = {0.f, 0.f, 0.f, 0.f, 0.f, 0.f, 0.f, 0.f};
    for (int base = beg; base < end; base += WAVE) {
        int e = base + lane;
        bool valid = (e < end);
        int sid = valid ? esrc[e] : 0;
        float wgt = 0.f;
        if (valid) {
            float v = as_[sid] + adn;
            v = (v > 0.f) ? v : 0.2f * v;
            wgt = __expf(v - m) * rden;
        }
        gather_accum_h(xw, q, g, min(WAVE, end - base), sid, wgt, acc);
    }
    finish_store_q(acc, bias, out, n, q, g);
}

// ------------------------------- launch ------------------------------------

extern "C" void kernel_launch(void* const* d_in, const int* in_sizes, int n_in,
                              void* d_out, int out_size, void* d_ws, size_t ws_size,
                              hipStream_t stream) {
    const float* x   = (const float*)d_in[0];
    const int*   ei  = (const int*)d_in[1];
    const float* W1  = (const float*)d_in[2];
    const float* b1  = (const float*)d_in[3];
    const float* Wg1 = (const float*)d_in[4];
    const float* as1 = (const float*)d_in[5];
    const float* ad1 = (const float*)d_in[6];
    const float* bg1 = (const float*)d_in[7];
    const float* W2  = (const float*)d_in[8];
    const float* b2  = (const float*)d_in[9];
    const float* Wg2 = (const float*)d_in[10];
    const float* as2 = (const float*)d_in[11];
    const float* ad2 = (const float*)d_in[12];
    const float* bg2 = (const float*)d_in[13];
    const float* Wo  = (const float*)d_in[14];
    const float* bo  = (const float*)d_in[15];

    const int Nn = in_sizes[0] / 128;
    const int E  = in_sizes[1] / 2;
    const int Et = E + Nn;
    const int H  = 128;

    float* outH = (float*)d_out;
    float* outZ = outH + (size_t)Nn * H;

    char* p = (char*)d_ws;
    auto carve = [&](size_t bytes) {
        char* r = p;
        p += (bytes + 255) & ~(size_t)255;
        return r;
    };
    __half* bufA = (__half*)carve((size_t)Nn * H * sizeof(__half));  // xw (fp16)
    float* alS   = (float*)carve((size_t)Nn * sizeof(float));
    float* alD   = (float*)carve((size_t)Nn * sizeof(float));
    float* inv   = (float*)carve((size_t)Nn * sizeof(float));
    int*   deg   = (int*)carve((size_t)Nn * sizeof(int));
    int*   rowp  = (int*)carve((size_t)(Nn + 1) * sizeof(int));
    int*   cur   = (int*)carve((size_t)Nn * sizeof(int));
    int*   bsums = (int*)carve(256 * sizeof(int));
    int*   esrc  = (int*)carve((size_t)Et * sizeof(int));
    (void)ws_size; (void)n_in; (void)out_size;

    const int nb = (Nn + 255) / 256;
    const int ebk = (Et + 255) / 256;
    const int aggBlocks = (Nn * WAVE + 255) / 256;
    const int gemmB128 = (Nn + 31) / 32;
    const int gemmB64  = (Nn + 63) / 64;

    k_zero_i32<<<nb, 256, 0, stream>>>(deg, Nn);
    k_hist<<<ebk, 256, 0, stream>>>(ei, deg, E, Et);
    k_scan1<<<nb, 256, 0, stream>>>(deg, bsums, Nn);
    k_scan2<<<1, 256, 0, stream>>>(bsums, nb);
    k_scan3<<<nb, 256, 0, stream>>>(deg, bsums, rowp, cur, inv, Nn, Et);
    k_scatter<<<ebk, 256, 0, stream>>>(ei, cur, esrc, E, Et);

    gemm_k128<128, __half><<<gemmB128, 256, 0, stream>>>(x, W1, nullptr, bufA, Nn, 0);
    k_gcn_agg<<<aggBlocks, 256, 0, stream>>>(bufA, rowp, esrc, inv, b1, outH, Nn);

    gemm_k128<128, __half><<<gemmB128, 256, 0, stream>>>(outH, Wg1, nullptr, bufA, Nn, 0);
    k_alpha<<<aggBlocks, 256, 0, stream>>>(bufA, as1, ad1, alS, alD, Nn);
    k_gat_agg<<<aggBlocks, 256, 0, stream>>>(bufA, rowp, esrc, alS, alD, bg1, outH, Nn);

    gemm_k128<128, __half><<<gemmB128, 256, 0, stream>>>(outH, W2, nullptr, bufA, Nn, 0);
    k_gcn_agg<<<aggBlocks, 256, 0, stream>>>(bufA, rowp, esrc, inv, b2, outH, Nn);

    gemm_k128<128, __half><<<gemmB128, 256, 0, stream>>>(outH, Wg2, nullptr, bufA, Nn, 0);
    k_alpha<<<aggBlocks, 256, 0, stream>>>(bufA, as2, ad2, alS, alD, Nn);
    k_gat_agg<<<aggBlocks, 256, 0, stream>>>(bufA, rowp, esrc, alS, alD, bg2, outH, Nn);

    gemm_k128<64, float><<<gemmB64, 256, 0, stream>>>(outH, Wo, bo, outZ, Nn, 0);
}

// Round 6
// 530.018 us; speedup vs baseline: 1.1738x; 1.0626x over previous
//
#include <hip/hip_runtime.h>
#include <hip/hip_bf16.h>
#include <hip/hip_fp16.h>

// ---------------------------------------------------------------------------
// GNN: h = relu(GCN(x)); h = relu(GAT(h)); h = relu(GCN(h)); h = relu(GAT(h));
//      z = h @ Wo + bo.  Outputs: [h (N*128), z (N*64)] fp32.
// R6: latency attack on agg (bytes were NOT the limiter: dur invariant R2/R4/R5).
//   - gather pipeline: rounds of 32 edges, up to 8 dwordx4 load-groups issued
//     under WAVE-UNIFORM guards before accumulation (deg~17 -> 5 loads in
//     flight vs 1 in the old tail).
//   - GAT deg<=64 fused path: esrc + as_ loaded ONCE, logit kept in register
//     (R3's failure was the predicated shfl tail - bpermute from inactive
//     lane - not this fusion; all shfls here are in uniform control flow).
// ---------------------------------------------------------------------------

#define WAVE 64

// ------------------------------ graph build --------------------------------

__global__ void k_zero_i32(int* __restrict__ p, int n) {
    int i = blockIdx.x * 256 + threadIdx.x;
    if (i < n) p[i] = 0;
}

__global__ void k_hist(const int* __restrict__ ei, int* __restrict__ deg,
                       int E, int Et) {
    int e = blockIdx.x * 256 + threadIdx.x;
    if (e >= Et) return;
    int d = (e < E) ? ei[E + e] : (e - E);
    atomicAdd(&deg[d], 1);
}

__global__ void k_scan1(const int* __restrict__ deg, int* __restrict__ bs, int n) {
    __shared__ int tmp[256];
    int tid = threadIdx.x;
    int gid = blockIdx.x * 256 + tid;
    tmp[tid] = (gid < n) ? deg[gid] : 0;
    __syncthreads();
    for (int off = 128; off > 0; off >>= 1) {
        if (tid < off) tmp[tid] += tmp[tid + off];
        __syncthreads();
    }
    if (tid == 0) bs[blockIdx.x] = tmp[0];
}

__global__ void k_scan2(int* __restrict__ bs, int nb) {
    __shared__ int tmp[256];
    int tid = threadIdx.x;
    int v = (tid < nb) ? bs[tid] : 0;
    tmp[tid] = v;
    __syncthreads();
    for (int off = 1; off < 256; off <<= 1) {
        int t = (tid >= off) ? tmp[tid - off] : 0;
        __syncthreads();
        tmp[tid] += t;
        __syncthreads();
    }
    if (tid < nb) bs[tid] = tmp[tid] - v;   // exclusive
}

__global__ void k_scan3(const int* __restrict__ deg, const int* __restrict__ bs,
                        int* __restrict__ rowp, int* __restrict__ cur,
                        float* __restrict__ inv, int n, int total) {
    __shared__ int tmp[256];
    int tid = threadIdx.x;
    int gid = blockIdx.x * 256 + tid;
    int v = (gid < n) ? deg[gid] : 0;
    tmp[tid] = v;
    __syncthreads();
    for (int off = 1; off < 256; off <<= 1) {
        int t = (tid >= off) ? tmp[tid - off] : 0;
        __syncthreads();
        tmp[tid] += t;
        __syncthreads();
    }
    if (gid < n) {
        int rp = bs[blockIdx.x] + tmp[tid] - v;
        rowp[gid] = rp;
        cur[gid] = rp;
        inv[gid] = rsqrtf((float)v);
    }
    if (gid == 0) rowp[n] = total;
}

__global__ void k_scatter(const int* __restrict__ ei, int* __restrict__ cur,
                          int* __restrict__ esrc, int E, int Et) {
    int e = blockIdx.x * 256 + threadIdx.x;
    if (e >= Et) return;
    int s, d;
    if (e < E) { s = ei[e]; d = ei[E + e]; }
    else       { s = d = e - E; }
    int pos = atomicAdd(&cur[d], 1);
    esrc[pos] = s;
}

// ------------------------------ GEMM (fp32 in, fp32/fp16 out) --------------

template <int NC, typename OT>
__global__ __launch_bounds__(256) void gemm_k128(
    const float* __restrict__ A, const float* __restrict__ W,
    const float* __restrict__ bias, OT* __restrict__ out,
    int M, int do_relu) {
    constexpr int TR = 4096 / NC;
    constexpr int CG = NC / 4;
    constexpr int AP = 132;
    __shared__ float Ws[64 * NC];
    __shared__ float As[TR * AP];

    const int tid = threadIdx.x;
    const int cg = tid % CG;
    const int rg = tid / CG;
    const int row0 = blockIdx.x * TR;

    for (int i = tid; i < TR * 32; i += 256) {
        int r = i >> 5, c4 = i & 31;
        int gr = row0 + r;
        float4 v = make_float4(0.f, 0.f, 0.f, 0.f);
        if (gr < M) v = ((const float4*)A)[(size_t)gr * 32 + c4];
        *((float4*)(As + r * AP + c4 * 4)) = v;
    }

    float acc[4][4] = {{0.f}};
    for (int half = 0; half < 2; ++half) {
        __syncthreads();
        for (int i = tid; i < 64 * NC / 4; i += 256)
            ((float4*)Ws)[i] = ((const float4*)W)[half * (64 * NC / 4) + i];
        __syncthreads();
#pragma unroll
        for (int k4 = 0; k4 < 16; ++k4) {
            float4 aa[4];
#pragma unroll
            for (int i = 0; i < 4; ++i)
                aa[i] = *((const float4*)(As + (rg * 4 + i) * AP + half * 64 + k4 * 4));
#pragma unroll
            for (int kk = 0; kk < 4; ++kk) {
                float4 w = ((const float4*)Ws)[(k4 * 4 + kk) * CG + cg];
#pragma unroll
                for (int i = 0; i < 4; ++i) {
                    float av = ((const float*)&aa[i])[kk];
                    acc[i][0] = fmaf(av, w.x, acc[i][0]);
                    acc[i][1] = fmaf(av, w.y, acc[i][1]);
                    acc[i][2] = fmaf(av, w.z, acc[i][2]);
                    acc[i][3] = fmaf(av, w.w, acc[i][3]);
                }
            }
        }
    }

    float4 b4 = make_float4(0.f, 0.f, 0.f, 0.f);
    if (bias) b4 = ((const float4*)bias)[cg];
#pragma unroll
    for (int i = 0; i < 4; ++i) {
        int gr = row0 + rg * 4 + i;
        if (gr < M) {
            float rx = acc[i][0] + b4.x;
            float ry = acc[i][1] + b4.y;
            float rz = acc[i][2] + b4.z;
            float rw = acc[i][3] + b4.w;
            if (do_relu) {
                rx = fmaxf(rx, 0.f); ry = fmaxf(ry, 0.f);
                rz = fmaxf(rz, 0.f); rw = fmaxf(rw, 0.f);
            }
            if constexpr (sizeof(OT) == 2) {
                __half2* orow = (__half2*)((__half*)out + (size_t)gr * NC);
                orow[cg * 2]     = __floats2half2_rn(rx, ry);
                orow[cg * 2 + 1] = __floats2half2_rn(rz, rw);
            } else {
                ((float4*)out)[(size_t)gr * CG + cg] =
                    make_float4(rx, ry, rz, rw);
            }
        }
    }
}

// --------------------------- aggregation kernels ---------------------------
// One wave per destination node. lane = 16*g + q: quarter-wave g handles edge
// j+g of each group of 4; lane owns fp16 features 8q..8q+7 (16 B dwordx4).
// INVARIANT: lanes with index >= cnt hold wgt == 0 and a valid sid (0 ok);
// all 64 lanes active; every guard below is wave-uniform so shfl always
// executes with full exec (R3 lesson: bpermute from inactive lane undefined).
// shfl idx may exceed cnt by <=2 (those lanes contribute wgt=0).

__device__ __forceinline__ void gather_accum_h(
    const __half* __restrict__ xw, int q, int g, int cnt, int sid, float wgt,
    float acc[8]) {
    for (int base = 0; base < cnt; base += 32) {
        int c = cnt - base;           // wave-uniform
        float4 x[8];
        float w[8];
        // issue phase: up to 8 independent dwordx4 loads in flight
#pragma unroll
        for (int u = 0; u < 8; ++u) {
            if (u * 4 < c) {          // uniform guard
                int idx = base + 4 * u + g;
                int s = __shfl(sid, idx);
                w[u] = __shfl(wgt, idx);
                x[u] = *(const float4*)(xw + (size_t)s * 128 + q * 8);
            }
        }
        // accumulate phase
#pragma unroll
        for (int u = 0; u < 8; ++u) {
            if (u * 4 < c) {          // uniform guard
                const __half2* h2 = (const __half2*)&x[u];
#pragma unroll
                for (int i = 0; i < 4; ++i) {
                    float2 cc = __half22float2(h2[i]);
                    acc[2 * i]     = fmaf(w[u], cc.x, acc[2 * i]);
                    acc[2 * i + 1] = fmaf(w[u], cc.y, acc[2 * i + 1]);
                }
            }
        }
    }
}

__device__ __forceinline__ void finish_store_q(
    float acc[8], const float* __restrict__ bias, float* __restrict__ out,
    int n, int q, int g) {
#pragma unroll
    for (int i = 0; i < 8; ++i) {
        acc[i] += __shfl_xor(acc[i], 16);
        acc[i] += __shfl_xor(acc[i], 32);
    }
    if (g == 0) {
        float4 b0 = ((const float4*)bias)[q * 2];
        float4 b1 = ((const float4*)bias)[q * 2 + 1];
        float4 r0, r1;
        r0.x = fmaxf(acc[0] + b0.x, 0.f);
        r0.y = fmaxf(acc[1] + b0.y, 0.f);
        r0.z = fmaxf(acc[2] + b0.z, 0.f);
        r0.w = fmaxf(acc[3] + b0.w, 0.f);
        r1.x = fmaxf(acc[4] + b1.x, 0.f);
        r1.y = fmaxf(acc[5] + b1.y, 0.f);
        r1.z = fmaxf(acc[6] + b1.z, 0.f);
        r1.w = fmaxf(acc[7] + b1.w, 0.f);
        float4* orow = (float4*)(out + (size_t)n * 128);
        orow[q * 2]     = r0;
        orow[q * 2 + 1] = r1;
    }
}

__global__ __launch_bounds__(256) void k_gcn_agg(
    const __half* __restrict__ xw, const int* __restrict__ rowp,
    const int* __restrict__ esrc, const float* __restrict__ inv,
    const float* __restrict__ bias, float* __restrict__ out, int Nn) {
    int gid = blockIdx.x * 256 + threadIdx.x;
    int n = gid >> 6, lane = gid & 63;
    if (n >= Nn) return;
    int q = lane & 15, g = lane >> 4;
    int beg = rowp[n], end = rowp[n + 1];
    float invd = inv[n];
    float acc[8] = {0.f, 0.f, 0.f, 0.f, 0.f, 0.f, 0.f, 0.f};
    for (int base = beg; base < end; base += WAVE) {
        int e = base + lane;
        bool valid = (e < end);
        int sid = valid ? esrc[e] : 0;
        float c = valid ? invd * inv[sid] : 0.f;
        gather_accum_h(xw, q, g, min(WAVE, end - base), sid, c, acc);
    }
    finish_store_q(acc, bias, out, n, q, g);
}

__global__ __launch_bounds__(256) void k_alpha(
    const __half* __restrict__ xw, const float* __restrict__ asrc,
    const float* __restrict__ adst, float* __restrict__ s_out,
    float* __restrict__ d_out_, int Nn) {
    int gid = blockIdx.x * 256 + threadIdx.x;
    int n = gid >> 6, lane = gid & 63;
    if (n >= Nn) return;
    float2 xv = __half22float2(*(const __half2*)(xw + (size_t)n * 128 + lane * 2));
    float2 sa = ((const float2*)asrc)[lane];
    float2 da = ((const float2*)adst)[lane];
    float s = fmaf(xv.y, sa.y, xv.x * sa.x);
    float d = fmaf(xv.y, da.y, xv.x * da.x);
#pragma unroll
    for (int off = 32; off > 0; off >>= 1) {
        s += __shfl_xor(s, off);
        d += __shfl_xor(d, off);
    }
    if (lane == 0) { s_out[n] = s; d_out_[n] = d; }
}

__global__ __launch_bounds__(256) void k_gat_agg(
    const __half* __restrict__ xw, const int* __restrict__ rowp,
    const int* __restrict__ esrc, const float* __restrict__ as_,
    const float* __restrict__ ad_, const float* __restrict__ bias,
    float* __restrict__ out, int Nn) {
    int gid = blockIdx.x * 256 + threadIdx.x;
    int n = gid >> 6, lane = gid & 63;
    if (n >= Nn) return;
    int q = lane & 15, g = lane >> 4;
    int beg = rowp[n], end = rowp[n + 1];
    int deg = end - beg;
    float adn = ad_[n];
    float acc[8] = {0.f, 0.f, 0.f, 0.f, 0.f, 0.f, 0.f, 0.f};

    if (deg <= WAVE) {
        // fused path (deg<=64, ~all nodes): edge data loaded once, logit in reg
        bool valid = (lane < deg);
        int sid = 0;
        float v = -1e30f;
        if (valid) {
            sid = esrc[beg + lane];
            float t = as_[sid] + adn;
            v = (t > 0.f) ? t : 0.2f * t;
        }
        // wave reductions: all 64 lanes active
        float m = v;
#pragma unroll
        for (int off = 32; off > 0; off >>= 1) m = fmaxf(m, __shfl_xor(m, off));
        float ex = valid ? __expf(v - m) : 0.f;
        float ssum = ex;
#pragma unroll
        for (int off = 32; off > 0; off >>= 1) ssum += __shfl_xor(ssum, off);
        float wgt = ex * (1.f / ssum);   // invalid lanes: 0
        gather_accum_h(xw, q, g, deg, sid, wgt, acc);
    } else {
        // generic two-pass path (deg>64: essentially never at E/N=16)
        float m = -1e30f, ssum = 0.f;
        for (int e = beg + lane; e < end; e += WAVE) {
            float v = as_[esrc[e]] + adn;
            v = (v > 0.f) ? v : 0.2f * v;
            float mn = fmaxf(m, v);
            ssum = ssum * __expf(m - mn) + __expf(v - mn);
            m = mn;
        }
#pragma unroll
        for (int off = 32; off > 0; off >>= 1) {
            float mo = __shfl_xor(m, off);
            float so = __shfl_xor(ssum, off);
            float mn = fmaxf(m, mo);
            ssum = ssum * __expf(m - mn) + so * __expf(mo - mn);
            m = mn;
        }
        float rden = 1.f / ssum;
        for (int base = beg; base < end; base += WAVE) {
            int e = base + lane;
            bool valid = (e < end);
            int sid = valid ? esrc[e] : 0;
            float wgt = 0.f;
            if (valid) {
                float v = as_[sid] + adn;
                v = (v > 0.f) ? v : 0.2f * v;
                wgt = __expf(v - m) * rden;
            }
            gather_accum_h(xw, q, g, min(WAVE, end - base), sid, wgt, acc);
        }
    }
    finish_store_q(acc, bias, out, n, q, g);
}

// ------------------------------- launch ------------------------------------

extern "C" void kernel_launch(void* const* d_in, const int* in_sizes, int n_in,
                              void* d_out, int out_size, void* d_ws, size_t ws_size,
                              hipStream_t stream) {
    const float* x   = (const float*)d_in[0];
    const int*   ei  = (const int*)d_in[1];
    const float* W1  = (const float*)d_in[2];
    const float* b1  = (const float*)d_in[3];
    const float* Wg1 = (const float*)d_in[4];
    const float* as1 = (const float*)d_in[5];
    const float* ad1 = (const float*)d_in[6];
    const float* bg1 = (const float*)d_in[7];
    const float* W2  = (const float*)d_in[8];
    const float* b2  = (const float*)d_in[9];
    const float* Wg2 = (const float*)d_in[10];
    const float* as2 = (const float*)d_in[11];
    const float* ad2 = (const float*)d_in[12];
    const float* bg2 = (const float*)d_in[13];
    const float* Wo  = (const float*)d_in[14];
    const float* bo  = (const float*)d_in[15];

    const int Nn = in_sizes[0] / 128;
    const int E  = in_sizes[1] / 2;
    const int Et = E + Nn;
    const int H  = 128;

    float* outH = (float*)d_out;
    float* outZ = outH + (size_t)Nn * H;

    char* p = (char*)d_ws;
    auto carve = [&](size_t bytes) {
        char* r = p;
        p += (bytes + 255) & ~(size_t)255;
        return r;
    };
    __half* bufA = (__half*)carve((size_t)Nn * H * sizeof(__half));  // xw (fp16)
    float* alS   = (float*)carve((size_t)Nn * sizeof(float));
    float* alD   = (float*)carve((size_t)Nn * sizeof(float));
    float* inv   = (float*)carve((size_t)Nn * sizeof(float));
    int*   deg   = (int*)carve((size_t)Nn * sizeof(int));
    int*   rowp  = (int*)carve((size_t)(Nn + 1) * sizeof(int));
    int*   cur   = (int*)carve((size_t)Nn * sizeof(int));
    int*   bsums = (int*)carve(256 * sizeof(int));
    int*   esrc  = (int*)carve((size_t)Et * sizeof(int));
    (void)ws_size; (void)n_in; (void)out_size;

    const int nb = (Nn + 255) / 256;
    const int ebk = (Et + 255) / 256;
    const int aggBlocks = (Nn * WAVE + 255) / 256;
    const int gemmB128 = (Nn + 31) / 32;
    const int gemmB64  = (Nn + 63) / 64;

    k_zero_i32<<<nb, 256, 0, stream>>>(deg, Nn);
    k_hist<<<ebk, 256, 0, stream>>>(ei, deg, E, Et);
    k_scan1<<<nb, 256, 0, stream>>>(deg, bsums, Nn);
    k_scan2<<<1, 256, 0, stream>>>(bsums, nb);
    k_scan3<<<nb, 256, 0, stream>>>(deg, bsums, rowp, cur, inv, Nn, Et);
    k_scatter<<<ebk, 256, 0, stream>>>(ei, cur, esrc, E, Et);

    gemm_k128<128, __half><<<gemmB128, 256, 0, stream>>>(x, W1, nullptr, bufA, Nn, 0);
    k_gcn_agg<<<aggBlocks, 256, 0, stream>>>(bufA, rowp, esrc, inv, b1, outH, Nn);

    gemm_k128<128, __half><<<gemmB128, 256, 0, stream>>>(outH, Wg1, nullptr, bufA, Nn, 0);
    k_alpha<<<aggBlocks, 256, 0, stream>>>(bufA, as1, ad1, alS, alD, Nn);
    k_gat_agg<<<aggBlocks, 256, 0, stream>>>(bufA, rowp, esrc, alS, alD, bg1, outH, Nn);

    gemm_k128<128, __half><<<gemmB128, 256, 0, stream>>>(outH, W2, nullptr, bufA, Nn, 0);
    k_gcn_agg<<<aggBlocks, 256, 0, stream>>>(bufA, rowp, esrc, inv, b2, outH, Nn);

    gemm_k128<128, __half><<<gemmB128, 256, 0, stream>>>(outH, Wg2, nullptr, bufA, Nn, 0);
    k_alpha<<<aggBlocks, 256, 0, stream>>>(bufA, as2, ad2, alS, alD, Nn);
    k_gat_agg<<<aggBlocks, 256, 0, stream>>>(bufA, rowp, esrc, alS, alD, bg2, outH, Nn);

    gemm_k128<64, float><<<gemmB64, 256, 0, stream>>>(outH, Wo, bo, outZ, Nn, 0);
}

// Round 7
// 479.032 us; speedup vs baseline: 1.2988x; 1.1064x over previous
//
#include <hip/hip_runtime.h>
#include <hip/hip_bf16.h>
#include <hip/hip_fp16.h>

// ---------------------------------------------------------------------------
// GNN: h = relu(GCN(x)); h = relu(GAT(h)); h = relu(GCN(h)); h = relu(GAT(h));
//      z = h @ Wo + bo.  Outputs: [h (N*128), z (N*64)] fp32.
// R7: graph build reworked. Old k_scatter was a write-amplification floor
//     (850k random 4B writes -> 54 MB HBM, ~1 TB/s, 57 us). New build is a
//     two-level bucket sort: coarse partition by dst>>8 into 196 buckets
//     (contiguous per-block runs, near-full-line writes), then per-bucket
//     LDS counting sort emitting rowp/deg/inv and a bucket-local esrc
//     scatter (17 KB window -> L2-absorbed, lines written once).
// ---------------------------------------------------------------------------

#define WAVE 64
#define BK 256        // nodes per bucket
#define CHUNK 4096    // edges per k_bscatter block

__global__ void k_zero_i32(int* __restrict__ p, int n) {
    int i = blockIdx.x * 256 + threadIdx.x;
    if (i < n) p[i] = 0;
}

// ------------------------------ graph build --------------------------------
// edge e in [0,E): (s,d) = (ei[e], ei[E+e]); e in [E,Et): self-loop (e-E,e-E)

__global__ __launch_bounds__(256) void k_bhist(
    const int* __restrict__ ei, int* __restrict__ bcnt,
    int E, int Et, int nbuck) {
    __shared__ int hist[256];
    int tid = threadIdx.x;
    if (tid < nbuck) hist[tid] = 0;
    __syncthreads();
    for (int e = blockIdx.x * 256 + tid; e < Et; e += gridDim.x * 256) {
        int d = (e < E) ? ei[E + e] : (e - E);
        atomicAdd(&hist[d >> 8], 1);
    }
    __syncthreads();
    if (tid < nbuck && hist[tid] > 0) atomicAdd(&bcnt[tid], hist[tid]);
}

// exclusive scan of bcnt[nbuck] -> bbase[0..nbuck], bcur[j]=bbase[j]
__global__ void k_bscan(const int* __restrict__ bcnt, int* __restrict__ bbase,
                        int* __restrict__ bcur, int nbuck) {
    __shared__ int tmp[256];
    int tid = threadIdx.x;
    int v = (tid < nbuck) ? bcnt[tid] : 0;
    tmp[tid] = v;
    __syncthreads();
    for (int off = 1; off < 256; off <<= 1) {
        int t = (tid >= off) ? tmp[tid - off] : 0;
        __syncthreads();
        tmp[tid] += t;
        __syncthreads();
    }
    if (tid < nbuck) {
        int excl = tmp[tid] - v;
        bbase[tid] = excl;
        bcur[tid] = excl;
        if (tid == nbuck - 1) bbase[nbuck] = tmp[tid];
    }
}

// coarse partition: (s,d) pairs grouped by dst>>8, per-block contiguous runs
__global__ __launch_bounds__(256) void k_bscatter(
    const int* __restrict__ ei, int* __restrict__ bcur,
    int2* __restrict__ ebuf, int E, int Et, int nbuck) {
    __shared__ int hist[256];
    __shared__ int base[256];
    __shared__ int off[256];
    constexpr int PT = CHUNK / 256;   // 16 edges per thread
    int tid = threadIdx.x;
    int cb = blockIdx.x * CHUNK;
    if (tid < nbuck) { hist[tid] = 0; off[tid] = 0; }
    __syncthreads();

    int sv[PT], dv[PT];
#pragma unroll
    for (int i = 0; i < PT; ++i) {
        int e = cb + i * 256 + tid;
        int s = 0, d = -1;
        if (e < Et) {
            if (e < E) { s = ei[e]; d = ei[E + e]; }
            else       { s = d = e - E; }
            atomicAdd(&hist[d >> 8], 1);
        }
        sv[i] = s; dv[i] = d;
    }
    __syncthreads();
    if (tid < nbuck && hist[tid] > 0)
        base[tid] = atomicAdd(&bcur[tid], hist[tid]);
    __syncthreads();
#pragma unroll
    for (int i = 0; i < PT; ++i) {
        if (dv[i] >= 0) {
            int b = dv[i] >> 8;
            int pos = base[b] + atomicAdd(&off[b], 1);
            ebuf[pos] = make_int2(sv[i], dv[i]);
        }
    }
}

// per-bucket counting sort: emits rowp/inv and final esrc
__global__ __launch_bounds__(256) void k_csr(
    const int2* __restrict__ ebuf, const int* __restrict__ bbase,
    int* __restrict__ rowp, float* __restrict__ inv, int* __restrict__ esrc,
    int Nn, int Et) {
    __shared__ int hist[256];
    __shared__ int scan[256];
    __shared__ int cur[256];
    int tid = threadIdx.x;
    int b = blockIdx.x;
    int bb = bbase[b], cnt = bbase[b + 1] - bb;
    hist[tid] = 0;
    __syncthreads();
    for (int t = tid; t < cnt; t += 256)
        atomicAdd(&hist[ebuf[bb + t].y & 255], 1);
    __syncthreads();
    // exclusive scan over hist
    int v = hist[tid];
    scan[tid] = v;
    __syncthreads();
    for (int o = 1; o < 256; o <<= 1) {
        int t = (tid >= o) ? scan[tid - o] : 0;
        __syncthreads();
        scan[tid] += t;
        __syncthreads();
    }
    int excl = scan[tid] - v;
    int node = b * BK + tid;
    if (node < Nn) {
        rowp[node] = bb + excl;
        inv[node] = rsqrtf((float)v);
    }
    cur[tid] = excl;
    if (b == 0 && tid == 0) rowp[Nn] = Et;
    __syncthreads();
    for (int t = tid; t < cnt; t += 256) {
        int2 e = ebuf[bb + t];
        int pos = bb + atomicAdd(&cur[e.y & 255], 1);
        esrc[pos] = e.x;
    }
}

// ------------------------------ GEMM (fp32 in, fp32/fp16 out) --------------

template <int NC, typename OT>
__global__ __launch_bounds__(256) void gemm_k128(
    const float* __restrict__ A, const float* __restrict__ W,
    const float* __restrict__ bias, OT* __restrict__ out,
    int M, int do_relu) {
    constexpr int TR = 4096 / NC;
    constexpr int CG = NC / 4;
    constexpr int AP = 132;
    __shared__ float Ws[64 * NC];
    __shared__ float As[TR * AP];

    const int tid = threadIdx.x;
    const int cg = tid % CG;
    const int rg = tid / CG;
    const int row0 = blockIdx.x * TR;

    for (int i = tid; i < TR * 32; i += 256) {
        int r = i >> 5, c4 = i & 31;
        int gr = row0 + r;
        float4 v = make_float4(0.f, 0.f, 0.f, 0.f);
        if (gr < M) v = ((const float4*)A)[(size_t)gr * 32 + c4];
        *((float4*)(As + r * AP + c4 * 4)) = v;
    }

    float acc[4][4] = {{0.f}};
    for (int half = 0; half < 2; ++half) {
        __syncthreads();
        for (int i = tid; i < 64 * NC / 4; i += 256)
            ((float4*)Ws)[i] = ((const float4*)W)[half * (64 * NC / 4) + i];
        __syncthreads();
#pragma unroll
        for (int k4 = 0; k4 < 16; ++k4) {
            float4 aa[4];
#pragma unroll
            for (int i = 0; i < 4; ++i)
                aa[i] = *((const float4*)(As + (rg * 4 + i) * AP + half * 64 + k4 * 4));
#pragma unroll
            for (int kk = 0; kk < 4; ++kk) {
                float4 w = ((const float4*)Ws)[(k4 * 4 + kk) * CG + cg];
#pragma unroll
                for (int i = 0; i < 4; ++i) {
                    float av = ((const float*)&aa[i])[kk];
                    acc[i][0] = fmaf(av, w.x, acc[i][0]);
                    acc[i][1] = fmaf(av, w.y, acc[i][1]);
                    acc[i][2] = fmaf(av, w.z, acc[i][2]);
                    acc[i][3] = fmaf(av, w.w, acc[i][3]);
                }
            }
        }
    }

    float4 b4 = make_float4(0.f, 0.f, 0.f, 0.f);
    if (bias) b4 = ((const float4*)bias)[cg];
#pragma unroll
    for (int i = 0; i < 4; ++i) {
        int gr = row0 + rg * 4 + i;
        if (gr < M) {
            float rx = acc[i][0] + b4.x;
            float ry = acc[i][1] + b4.y;
            float rz = acc[i][2] + b4.z;
            float rw = acc[i][3] + b4.w;
            if (do_relu) {
                rx = fmaxf(rx, 0.f); ry = fmaxf(ry, 0.f);
                rz = fmaxf(rz, 0.f); rw = fmaxf(rw, 0.f);
            }
            if constexpr (sizeof(OT) == 2) {
                __half2* orow = (__half2*)((__half*)out + (size_t)gr * NC);
                orow[cg * 2]     = __floats2half2_rn(rx, ry);
                orow[cg * 2 + 1] = __floats2half2_rn(rz, rw);
            } else {
                ((float4*)out)[(size_t)gr * CG + cg] =
                    make_float4(rx, ry, rz, rw);
            }
        }
    }
}

// --------------------------- aggregation kernels ---------------------------
// One wave per destination node. lane = 16*g + q: quarter-wave g handles edge
// j+g of each group of 4; lane owns fp16 features 8q..8q+7 (16 B dwordx4).
// INVARIANT: lanes with index >= cnt hold wgt == 0 and a valid sid (0 ok);
// all 64 lanes active; every guard is wave-uniform so shfl always executes
// with full exec (R3 lesson: bpermute from inactive lane undefined).

__device__ __forceinline__ void gather_accum_h(
    const __half* __restrict__ xw, int q, int g, int cnt, int sid, float wgt,
    float acc[8]) {
    for (int base = 0; base < cnt; base += 32) {
        int c = cnt - base;           // wave-uniform
        float4 x[8];
        float w[8];
#pragma unroll
        for (int u = 0; u < 8; ++u) {
            if (u * 4 < c) {          // uniform guard
                int idx = base + 4 * u + g;
                int s = __shfl(sid, idx);
                w[u] = __shfl(wgt, idx);
                x[u] = *(const float4*)(xw + (size_t)s * 128 + q * 8);
            }
        }
#pragma unroll
        for (int u = 0; u < 8; ++u) {
            if (u * 4 < c) {          // uniform guard
                const __half2* h2 = (const __half2*)&x[u];
#pragma unroll
                for (int i = 0; i < 4; ++i) {
                    float2 cc = __half22float2(h2[i]);
                    acc[2 * i]     = fmaf(w[u], cc.x, acc[2 * i]);
                    acc[2 * i + 1] = fmaf(w[u], cc.y, acc[2 * i + 1]);
                }
            }
        }
    }
}

__device__ __forceinline__ void finish_store_q(
    float acc[8], const float* __restrict__ bias, float* __restrict__ out,
    int n, int q, int g) {
#pragma unroll
    for (int i = 0; i < 8; ++i) {
        acc[i] += __shfl_xor(acc[i], 16);
        acc[i] += __shfl_xor(acc[i], 32);
    }
    if (g == 0) {
        float4 b0 = ((const float4*)bias)[q * 2];
        float4 b1 = ((const float4*)bias)[q * 2 + 1];
        float4 r0, r1;
        r0.x = fmaxf(acc[0] + b0.x, 0.f);
        r0.y = fmaxf(acc[1] + b0.y, 0.f);
        r0.z = fmaxf(acc[2] + b0.z, 0.f);
        r0.w = fmaxf(acc[3] + b0.w, 0.f);
        r1.x = fmaxf(acc[4] + b1.x, 0.f);
        r1.y = fmaxf(acc[5] + b1.y, 0.f);
        r1.z = fmaxf(acc[6] + b1.z, 0.f);
        r1.w = fmaxf(acc[7] + b1.w, 0.f);
        float4* orow = (float4*)(out + (size_t)n * 128);
        orow[q * 2]     = r0;
        orow[q * 2 + 1] = r1;
    }
}

__global__ __launch_bounds__(256) void k_gcn_agg(
    const __half* __restrict__ xw, const int* __restrict__ rowp,
    const int* __restrict__ esrc, const float* __restrict__ inv,
    const float* __restrict__ bias, float* __restrict__ out, int Nn) {
    int gid = blockIdx.x * 256 + threadIdx.x;
    int n = gid >> 6, lane = gid & 63;
    if (n >= Nn) return;
    int q = lane & 15, g = lane >> 4;
    int beg = rowp[n], end = rowp[n + 1];
    float invd = inv[n];
    float acc[8] = {0.f, 0.f, 0.f, 0.f, 0.f, 0.f, 0.f, 0.f};
    for (int base = beg; base < end; base += WAVE) {
        int e = base + lane;
        bool valid = (e < end);
        int sid = valid ? esrc[e] : 0;
        float c = valid ? invd * inv[sid] : 0.f;
        gather_accum_h(xw, q, g, min(WAVE, end - base), sid, c, acc);
    }
    finish_store_q(acc, bias, out, n, q, g);
}

__global__ __launch_bounds__(256) void k_alpha(
    const __half* __restrict__ xw, const float* __restrict__ asrc,
    const float* __restrict__ adst, float* __restrict__ s_out,
    float* __restrict__ d_out_, int Nn) {
    int gid = blockIdx.x * 256 + threadIdx.x;
    int n = gid >> 6, lane = gid & 63;
    if (n >= Nn) return;
    float2 xv = __half22float2(*(const __half2*)(xw + (size_t)n * 128 + lane * 2));
    float2 sa = ((const float2*)asrc)[lane];
    float2 da = ((const float2*)adst)[lane];
    float s = fmaf(xv.y, sa.y, xv.x * sa.x);
    float d = fmaf(xv.y, da.y, xv.x * da.x);
#pragma unroll
    for (int off = 32; off > 0; off >>= 1) {
        s += __shfl_xor(s, off);
        d += __shfl_xor(d, off);
    }
    if (lane == 0) { s_out[n] = s; d_out_[n] = d; }
}

__global__ __launch_bounds__(256) void k_gat_agg(
    const __half* __restrict__ xw, const int* __restrict__ rowp,
    const int* __restrict__ esrc, const float* __restrict__ as_,
    const float* __restrict__ ad_, const float* __restrict__ bias,
    float* __restrict__ out, int Nn) {
    int gid = blockIdx.x * 256 + threadIdx.x;
    int n = gid >> 6, lane = gid & 63;
    if (n >= Nn) return;
    int q = lane & 15, g = lane >> 4;
    int beg = rowp[n], end = rowp[n + 1];
    int deg = end - beg;
    float adn = ad_[n];
    float acc[8] = {0.f, 0.f, 0.f, 0.f, 0.f, 0.f, 0.f, 0.f};

    if (deg <= WAVE) {
        // fused path (deg<=64, ~all nodes): edge data loaded once, logit in reg
        bool valid = (lane < deg);
        int sid = 0;
        float v = -1e30f;
        if (valid) {
            sid = esrc[beg + lane];
            float t = as_[sid] + adn;
            v = (t > 0.f) ? t : 0.2f * t;
        }
        float m = v;
#pragma unroll
        for (int off = 32; off > 0; off >>= 1) m = fmaxf(m, __shfl_xor(m, off));
        float ex = valid ? __expf(v - m) : 0.f;
        float ssum = ex;
#pragma unroll
        for (int off = 32; off > 0; off >>= 1) ssum += __shfl_xor(ssum, off);
        float wgt = ex * (1.f / ssum);   // invalid lanes: 0
        gather_accum_h(xw, q, g, deg, sid, wgt, acc);
    } else {
        // generic two-pass path (deg>64: essentially never at E/N=16)
        float m = -1e30f, ssum = 0.f;
        for (int e = beg + lane; e < end; e += WAVE) {
            float v = as_[esrc[e]] + adn;
            v = (v > 0.f) ? v : 0.2f * v;
            float mn = fmaxf(m, v);
            ssum = ssum * __expf(m - mn) + __expf(v - mn);
            m = mn;
        }
#pragma unroll
        for (int off = 32; off > 0; off >>= 1) {
            float mo = __shfl_xor(m, off);
            float so = __shfl_xor(ssum, off);
            float mn = fmaxf(m, mo);
            ssum = ssum * __expf(m - mn) + so * __expf(mo - mn);
            m = mn;
        }
        float rden = 1.f / ssum;
        for (int base = beg; base < end; base += WAVE) {
            int e = base + lane;
            bool valid = (e < end);
            int sid = valid ? esrc[e] : 0;
            float wgt = 0.f;
            if (valid) {
                float v = as_[sid] + adn;
                v = (v > 0.f) ? v : 0.2f * v;
                wgt = __expf(v - m) * rden;
            }
            gather_accum_h(xw, q, g, min(WAVE, end - base), sid, wgt, acc);
        }
    }
    finish_store_q(acc, bias, out, n, q, g);
}

// ------------------------------- launch ------------------------------------

extern "C" void kernel_launch(void* const* d_in, const int* in_sizes, int n_in,
                              void* d_out, int out_size, void* d_ws, size_t ws_size,
                              hipStream_t stream) {
    const float* x   = (const float*)d_in[0];
    const int*   ei  = (const int*)d_in[1];
    const float* W1  = (const float*)d_in[2];
    const float* b1  = (const float*)d_in[3];
    const float* Wg1 = (const float*)d_in[4];
    const float* as1 = (const float*)d_in[5];
    const float* ad1 = (const float*)d_in[6];
    const float* bg1 = (const float*)d_in[7];
    const float* W2  = (const float*)d_in[8];
    const float* b2  = (const float*)d_in[9];
    const float* Wg2 = (const float*)d_in[10];
    const float* as2 = (const float*)d_in[11];
    const float* ad2 = (const float*)d_in[12];
    const float* bg2 = (const float*)d_in[13];
    const float* Wo  = (const float*)d_in[14];
    const float* bo  = (const float*)d_in[15];

    const int Nn = in_sizes[0] / 128;
    const int E  = in_sizes[1] / 2;
    const int Et = E + Nn;
    const int H  = 128;
    const int nbuck = (Nn + BK - 1) / BK;   // 196

    float* outH = (float*)d_out;
    float* outZ = outH + (size_t)Nn * H;

    char* p = (char*)d_ws;
    auto carve = [&](size_t bytes) {
        char* r = p;
        p += (bytes + 255) & ~(size_t)255;
        return r;
    };
    __half* bufA = (__half*)carve((size_t)Nn * H * sizeof(__half));  // xw (fp16)
    float* alS   = (float*)carve((size_t)Nn * sizeof(float));
    float* alD   = (float*)carve((size_t)Nn * sizeof(float));
    float* inv   = (float*)carve((size_t)Nn * sizeof(float));
    int*   rowp  = (int*)carve((size_t)(Nn + 1) * sizeof(int));
    int*   esrc  = (int*)carve((size_t)Et * sizeof(int));
    int2*  ebuf  = (int2*)carve((size_t)Et * sizeof(int2));
    int*   bcnt  = (int*)carve((size_t)nbuck * sizeof(int));
    int*   bbase = (int*)carve((size_t)(nbuck + 1) * sizeof(int));
    int*   bcur  = (int*)carve((size_t)nbuck * sizeof(int));
    (void)ws_size; (void)n_in; (void)out_size;

    const int aggBlocks = (Nn * WAVE + 255) / 256;
    const int gemmB128 = (Nn + 31) / 32;
    const int gemmB64  = (Nn + 63) / 64;
    const int scatB = (Et + CHUNK - 1) / CHUNK;   // 208

    // graph build (two-level bucket sort)
    k_zero_i32<<<1, 256, 0, stream>>>(bcnt, nbuck);
    k_bhist<<<104, 256, 0, stream>>>(ei, bcnt, E, Et, nbuck);
    k_bscan<<<1, 256, 0, stream>>>(bcnt, bbase, bcur, nbuck);
    k_bscatter<<<scatB, 256, 0, stream>>>(ei, bcur, ebuf, E, Et, nbuck);
    k_csr<<<nbuck, 256, 0, stream>>>(ebuf, bbase, rowp, inv, esrc, Nn, Et);

    gemm_k128<128, __half><<<gemmB128, 256, 0, stream>>>(x, W1, nullptr, bufA, Nn, 0);
    k_gcn_agg<<<aggBlocks, 256, 0, stream>>>(bufA, rowp, esrc, inv, b1, outH, Nn);

    gemm_k128<128, __half><<<gemmB128, 256, 0, stream>>>(outH, Wg1, nullptr, bufA, Nn, 0);
    k_alpha<<<aggBlocks, 256, 0, stream>>>(bufA, as1, ad1, alS, alD, Nn);
    k_gat_agg<<<aggBlocks, 256, 0, stream>>>(bufA, rowp, esrc, alS, alD, bg1, outH, Nn);

    gemm_k128<128, __half><<<gemmB128, 256, 0, stream>>>(outH, W2, nullptr, bufA, Nn, 0);
    k_gcn_agg<<<aggBlocks, 256, 0, stream>>>(bufA, rowp, esrc, inv, b2, outH, Nn);

    gemm_k128<128, __half><<<gemmB128, 256, 0, stream>>>(outH, Wg2, nullptr, bufA, Nn, 0);
    k_alpha<<<aggBlocks, 256, 0, stream>>>(bufA, as2, ad2, alS, alD, Nn);
    k_gat_agg<<<aggBlocks, 256, 0, stream>>>(bufA, rowp, esrc, alS, alD, bg2, outH, Nn);

    gemm_k128<64, float><<<gemmB64, 256, 0, stream>>>(outH, Wo, bo, outZ, Nn, 0);
}

// Round 8
// 381.441 us; speedup vs baseline: 1.6311x; 1.2558x over previous
//
#include <hip/hip_runtime.h>
#include <hip/hip_bf16.h>
#include <hip/hip_fp16.h>

// ---------------------------------------------------------------------------
// GNN: h = relu(GCN(x)); h = relu(GAT(h)); h = relu(GCN(h)); h = relu(GAT(h));
//      z = h @ Wo + bo.  Outputs: [h (N*128), z (N*64)] fp32.
// R8: GEMMs moved to fp16 MFMA (no fp32 MFMA on CDNA4; vector fp32 GEMM was
//     ~40 TF x 5 dispatches ~= 200 us). W pre-transposed+converted to fp16;
//     A converted in-register; fp32 accumulation. GAT alpha (xw.asrc/adst)
//     fused into the GEMM epilogue from the fp32 accumulators. Build (R7
//     bucket sort) and agg (R6 pipelined gather) unchanged.
// ---------------------------------------------------------------------------

#define WAVE 64
#define BK 256        // nodes per bucket
#define CHUNK 4096    // edges per k_bscatter block

typedef _Float16 f16x8 __attribute__((ext_vector_type(8)));
typedef float f32x4 __attribute__((ext_vector_type(4)));

__global__ void k_zero_i32(int* __restrict__ p, int n) {
    int i = blockIdx.x * 256 + threadIdx.x;
    if (i < n) p[i] = 0;
}

// ------------------------------ graph build --------------------------------
// edge e in [0,E): (s,d) = (ei[e], ei[E+e]); e in [E,Et): self-loop (e-E,e-E)

__global__ __launch_bounds__(256) void k_bhist(
    const int* __restrict__ ei, int* __restrict__ bcnt,
    int E, int Et, int nbuck) {
    __shared__ int hist[256];
    int tid = threadIdx.x;
    if (tid < nbuck) hist[tid] = 0;
    __syncthreads();
    for (int e = blockIdx.x * 256 + tid; e < Et; e += gridDim.x * 256) {
        int d = (e < E) ? ei[E + e] : (e - E);
        atomicAdd(&hist[d >> 8], 1);
    }
    __syncthreads();
    if (tid < nbuck && hist[tid] > 0) atomicAdd(&bcnt[tid], hist[tid]);
}

__global__ void k_bscan(const int* __restrict__ bcnt, int* __restrict__ bbase,
                        int* __restrict__ bcur, int nbuck) {
    __shared__ int tmp[256];
    int tid = threadIdx.x;
    int v = (tid < nbuck) ? bcnt[tid] : 0;
    tmp[tid] = v;
    __syncthreads();
    for (int off = 1; off < 256; off <<= 1) {
        int t = (tid >= off) ? tmp[tid - off] : 0;
        __syncthreads();
        tmp[tid] += t;
        __syncthreads();
    }
    if (tid < nbuck) {
        int excl = tmp[tid] - v;
        bbase[tid] = excl;
        bcur[tid] = excl;
        if (tid == nbuck - 1) bbase[nbuck] = tmp[tid];
    }
}

__global__ __launch_bounds__(256) void k_bscatter(
    const int* __restrict__ ei, int* __restrict__ bcur,
    int2* __restrict__ ebuf, int E, int Et, int nbuck) {
    __shared__ int hist[256];
    __shared__ int base[256];
    __shared__ int off[256];
    constexpr int PT = CHUNK / 256;   // 16 edges per thread
    int tid = threadIdx.x;
    int cb = blockIdx.x * CHUNK;
    if (tid < nbuck) { hist[tid] = 0; off[tid] = 0; }
    __syncthreads();

    int sv[PT], dv[PT];
#pragma unroll
    for (int i = 0; i < PT; ++i) {
        int e = cb + i * 256 + tid;
        int s = 0, d = -1;
        if (e < Et) {
            if (e < E) { s = ei[e]; d = ei[E + e]; }
            else       { s = d = e - E; }
            atomicAdd(&hist[d >> 8], 1);
        }
        sv[i] = s; dv[i] = d;
    }
    __syncthreads();
    if (tid < nbuck && hist[tid] > 0)
        base[tid] = atomicAdd(&bcur[tid], hist[tid]);
    __syncthreads();
#pragma unroll
    for (int i = 0; i < PT; ++i) {
        if (dv[i] >= 0) {
            int b = dv[i] >> 8;
            int pos = base[b] + atomicAdd(&off[b], 1);
            ebuf[pos] = make_int2(sv[i], dv[i]);
        }
    }
}

__global__ __launch_bounds__(256) void k_csr(
    const int2* __restrict__ ebuf, const int* __restrict__ bbase,
    int* __restrict__ rowp, float* __restrict__ inv, int* __restrict__ esrc,
    int Nn, int Et) {
    __shared__ int hist[256];
    __shared__ int scan[256];
    __shared__ int cur[256];
    int tid = threadIdx.x;
    int b = blockIdx.x;
    int bb = bbase[b], cnt = bbase[b + 1] - bb;
    hist[tid] = 0;
    __syncthreads();
    for (int t = tid; t < cnt; t += 256)
        atomicAdd(&hist[ebuf[bb + t].y & 255], 1);
    __syncthreads();
    int v = hist[tid];
    scan[tid] = v;
    __syncthreads();
    for (int o = 1; o < 256; o <<= 1) {
        int t = (tid >= o) ? scan[tid - o] : 0;
        __syncthreads();
        scan[tid] += t;
        __syncthreads();
    }
    int excl = scan[tid] - v;
    int node = b * BK + tid;
    if (node < Nn) {
        rowp[node] = bb + excl;
        inv[node] = rsqrtf((float)v);
    }
    cur[tid] = excl;
    if (b == 0 && tid == 0) rowp[Nn] = Et;
    __syncthreads();
    for (int t = tid; t < cnt; t += 256) {
        int2 e = ebuf[bb + t];
        int pos = bb + atomicAdd(&cur[e.y & 255], 1);
        esrc[pos] = e.x;
    }
}

// -------------------- weight convert (fp32 -> fp16, transposed) ------------
// Wt layout: [0]W1t [16384]Wg1t [32768]W2t [49152]Wg2t [65536]Wot(64x128)
// Wt[n][k] = W[k][n]

__global__ void k_wcvt(const float* __restrict__ W1, const float* __restrict__ Wg1,
                       const float* __restrict__ W2, const float* __restrict__ Wg2,
                       const float* __restrict__ Wo, __half* __restrict__ Wt) {
    int i = blockIdx.x * 256 + threadIdx.x;   // 73728 total
    if (i < 65536) {
        int w = i >> 14;
        int j = i & 16383;
        int n = j >> 7, k = j & 127;
        const float* W = (w == 0) ? W1 : (w == 1) ? Wg1 : (w == 2) ? W2 : Wg2;
        Wt[i] = __float2half(W[k * 128 + n]);
    } else if (i < 73728) {
        int j = i - 65536;
        int n = j >> 7, k = j & 127;
        Wt[65536 + j] = __float2half(Wo[k * 64 + n]);
    }
}

// ------------------------------ MFMA GEMM ----------------------------------
// out[M x NC] = A(fp32 M x 128) @ W(fp16, given as Wt[n][k]) ; fp32 accum.
// Block: 4 waves x 32 rows = 128 rows. Wave: 2 m-tiles x NT n-tiles x 4 ksteps
// of mfma_f32_16x16x32_f16. A frag: lane m=lane&15, k=quad*8+j (dwordx4 x2 +
// cvt). B frag from LDS Wt: n=lane&15, k=quad*8+j (ds_read_b128, 136-half
// padded stride: 16B-aligned rows, 2-way banks). C/D: col=lane&15,
// row=quad*4+reg. If asrc!=null, alpha logits reduced from fp32 accumulators.

template <int NC, typename OT>
__global__ __launch_bounds__(256) void gemm_mfma(
    const float* __restrict__ A, const __half* __restrict__ Wt,
    const float* __restrict__ bias, OT* __restrict__ out,
    const float* __restrict__ asrc, const float* __restrict__ adst,
    float* __restrict__ alS, float* __restrict__ alD, int M) {
    constexpr int NT = NC / 16;
    constexpr int LDW = 136;
    __shared__ _Float16 Wl[NC * LDW];
    const int tid = threadIdx.x;
    const int wv = tid >> 6, lane = tid & 63;
    const int m16 = lane & 15, quad = lane >> 4;

    for (int i = tid; i < NC * 16; i += 256) {
        int r = i >> 4, c8 = i & 15;
        *(float4*)(&Wl[r * LDW + c8 * 8]) =
            *(const float4*)((const _Float16*)Wt + r * 128 + c8 * 8);
    }
    __syncthreads();

    const int row0 = blockIdx.x * 128 + wv * 32;

    f16x8 af[2][4];
#pragma unroll
    for (int mt = 0; mt < 2; ++mt) {
        int row = row0 + mt * 16 + m16;
        if (row > M - 1) row = M - 1;
        const float* ap = A + (size_t)row * 128 + quad * 8;
#pragma unroll
        for (int ks = 0; ks < 4; ++ks) {
            float4 lo = *(const float4*)(ap + ks * 32);
            float4 hi = *(const float4*)(ap + ks * 32 + 4);
            f16x8 v;
            v[0] = (_Float16)lo.x; v[1] = (_Float16)lo.y;
            v[2] = (_Float16)lo.z; v[3] = (_Float16)lo.w;
            v[4] = (_Float16)hi.x; v[5] = (_Float16)hi.y;
            v[6] = (_Float16)hi.z; v[7] = (_Float16)hi.w;
            af[mt][ks] = v;
        }
    }

    f32x4 acc[2][NT];
#pragma unroll
    for (int mt = 0; mt < 2; ++mt)
#pragma unroll
        for (int nt = 0; nt < NT; ++nt)
            acc[mt][nt] = (f32x4){0.f, 0.f, 0.f, 0.f};

#pragma unroll
    for (int ks = 0; ks < 4; ++ks) {
#pragma unroll
        for (int nt = 0; nt < NT; ++nt) {
            f16x8 bf = *(const f16x8*)(&Wl[(nt * 16 + m16) * LDW + ks * 32 + quad * 8]);
            acc[0][nt] = __builtin_amdgcn_mfma_f32_16x16x32_f16(
                af[0][ks], bf, acc[0][nt], 0, 0, 0);
            acc[1][nt] = __builtin_amdgcn_mfma_f32_16x16x32_f16(
                af[1][ks], bf, acc[1][nt], 0, 0, 0);
        }
    }

    // fused GAT alpha: s = xw.asrc, d = xw.adst per row (from fp32 accum)
    if (asrc) {
        float sa[NT], da[NT];
#pragma unroll
        for (int nt = 0; nt < NT; ++nt) {
            sa[nt] = asrc[nt * 16 + m16];
            da[nt] = adst[nt * 16 + m16];
        }
#pragma unroll
        for (int mt = 0; mt < 2; ++mt) {
#pragma unroll
            for (int r = 0; r < 4; ++r) {
                float s = 0.f, d = 0.f;
#pragma unroll
                for (int nt = 0; nt < NT; ++nt) {
                    s = fmaf(acc[mt][nt][r], sa[nt], s);
                    d = fmaf(acc[mt][nt][r], da[nt], d);
                }
#pragma unroll
                for (int off = 8; off > 0; off >>= 1) {
                    s += __shfl_xor(s, off);
                    d += __shfl_xor(d, off);
                }
                int row = row0 + mt * 16 + quad * 4 + r;
                if (m16 == 0 && row < M) { alS[row] = s; alD[row] = d; }
            }
        }
    }

#pragma unroll
    for (int mt = 0; mt < 2; ++mt) {
#pragma unroll
        for (int nt = 0; nt < NT; ++nt) {
#pragma unroll
            for (int r = 0; r < 4; ++r) {
                int row = row0 + mt * 16 + quad * 4 + r;
                if (row < M) {
                    float v = acc[mt][nt][r];
                    int col = nt * 16 + m16;
                    if constexpr (sizeof(OT) == 2) {
                        ((__half*)out)[(size_t)row * NC + col] = __float2half(v);
                    } else {
                        ((float*)out)[(size_t)row * NC + col] = v + bias[col];
                    }
                }
            }
        }
    }
}

// --------------------------- aggregation kernels ---------------------------
// One wave per destination node. lane = 16*g + q: quarter-wave g handles edge
// j+g of each group of 4; lane owns fp16 features 8q..8q+7 (16 B dwordx4).
// INVARIANT: lanes with index >= cnt hold wgt == 0 and a valid sid (0 ok);
// all 64 lanes active; every guard is wave-uniform so shfl always executes
// with full exec (R3 lesson: bpermute from inactive lane undefined).

__device__ __forceinline__ void gather_accum_h(
    const __half* __restrict__ xw, int q, int g, int cnt, int sid, float wgt,
    float acc[8]) {
    for (int base = 0; base < cnt; base += 32) {
        int c = cnt - base;           // wave-uniform
        float4 x[8];
        float w[8];
#pragma unroll
        for (int u = 0; u < 8; ++u) {
            if (u * 4 < c) {          // uniform guard
                int idx = base + 4 * u + g;
                int s = __shfl(sid, idx);
                w[u] = __shfl(wgt, idx);
                x[u] = *(const float4*)(xw + (size_t)s * 128 + q * 8);
            }
        }
#pragma unroll
        for (int u = 0; u < 8; ++u) {
            if (u * 4 < c) {          // uniform guard
                const __half2* h2 = (const __half2*)&x[u];
#pragma unroll
                for (int i = 0; i < 4; ++i) {
                    float2 cc = __half22float2(h2[i]);
                    acc[2 * i]     = fmaf(w[u], cc.x, acc[2 * i]);
                    acc[2 * i + 1] = fmaf(w[u], cc.y, acc[2 * i + 1]);
                }
            }
        }
    }
}

__device__ __forceinline__ void finish_store_q(
    float acc[8], const float* __restrict__ bias, float* __restrict__ out,
    int n, int q, int g) {
#pragma unroll
    for (int i = 0; i < 8; ++i) {
        acc[i] += __shfl_xor(acc[i], 16);
        acc[i] += __shfl_xor(acc[i], 32);
    }
    if (g == 0) {
        float4 b0 = ((const float4*)bias)[q * 2];
        float4 b1 = ((const float4*)bias)[q * 2 + 1];
        float4 r0, r1;
        r0.x = fmaxf(acc[0] + b0.x, 0.f);
        r0.y = fmaxf(acc[1] + b0.y, 0.f);
        r0.z = fmaxf(acc[2] + b0.z, 0.f);
        r0.w = fmaxf(acc[3] + b0.w, 0.f);
        r1.x = fmaxf(acc[4] + b1.x, 0.f);
        r1.y = fmaxf(acc[5] + b1.y, 0.f);
        r1.z = fmaxf(acc[6] + b1.z, 0.f);
        r1.w = fmaxf(acc[7] + b1.w, 0.f);
        float4* orow = (float4*)(out + (size_t)n * 128);
        orow[q * 2]     = r0;
        orow[q * 2 + 1] = r1;
    }
}

__global__ __launch_bounds__(256) void k_gcn_agg(
    const __half* __restrict__ xw, const int* __restrict__ rowp,
    const int* __restrict__ esrc, const float* __restrict__ inv,
    const float* __restrict__ bias, float* __restrict__ out, int Nn) {
    int gid = blockIdx.x * 256 + threadIdx.x;
    int n = gid >> 6, lane = gid & 63;
    if (n >= Nn) return;
    int q = lane & 15, g = lane >> 4;
    int beg = rowp[n], end = rowp[n + 1];
    float invd = inv[n];
    float acc[8] = {0.f, 0.f, 0.f, 0.f, 0.f, 0.f, 0.f, 0.f};
    for (int base = beg; base < end; base += WAVE) {
        int e = base + lane;
        bool valid = (e < end);
        int sid = valid ? esrc[e] : 0;
        float c = valid ? invd * inv[sid] : 0.f;
        gather_accum_h(xw, q, g, min(WAVE, end - base), sid, c, acc);
    }
    finish_store_q(acc, bias, out, n, q, g);
}

__global__ __launch_bounds__(256) void k_gat_agg(
    const __half* __restrict__ xw, const int* __restrict__ rowp,
    const int* __restrict__ esrc, const float* __restrict__ as_,
    const float* __restrict__ ad_, const float* __restrict__ bias,
    float* __restrict__ out, int Nn) {
    int gid = blockIdx.x * 256 + threadIdx.x;
    int n = gid >> 6, lane = gid & 63;
    if (n >= Nn) return;
    int q = lane & 15, g = lane >> 4;
    int beg = rowp[n], end = rowp[n + 1];
    int deg = end - beg;
    float adn = ad_[n];
    float acc[8] = {0.f, 0.f, 0.f, 0.f, 0.f, 0.f, 0.f, 0.f};

    if (deg <= WAVE) {
        // fused path (deg<=64, ~all nodes): edge data loaded once, logit in reg
        bool valid = (lane < deg);
        int sid = 0;
        float v = -1e30f;
        if (valid) {
            sid = esrc[beg + lane];
            float t = as_[sid] + adn;
            v = (t > 0.f) ? t : 0.2f * t;
        }
        float m = v;
#pragma unroll
        for (int off = 32; off > 0; off >>= 1) m = fmaxf(m, __shfl_xor(m, off));
        float ex = valid ? __expf(v - m) : 0.f;
        float ssum = ex;
#pragma unroll
        for (int off = 32; off > 0; off >>= 1) ssum += __shfl_xor(ssum, off);
        float wgt = ex * (1.f / ssum);   // invalid lanes: 0
        gather_accum_h(xw, q, g, deg, sid, wgt, acc);
    } else {
        // generic two-pass path (deg>64: essentially never at E/N=16)
        float m = -1e30f, ssum = 0.f;
        for (int e = beg + lane; e < end; e += WAVE) {
            float v = as_[esrc[e]] + adn;
            v = (v > 0.f) ? v : 0.2f * v;
            float mn = fmaxf(m, v);
            ssum = ssum * __expf(m - mn) + __expf(v - mn);
            m = mn;
        }
#pragma unroll
        for (int off = 32; off > 0; off >>= 1) {
            float mo = __shfl_xor(m, off);
            float so = __shfl_xor(ssum, off);
            float mn = fmaxf(m, mo);
            ssum = ssum * __expf(m - mn) + so * __expf(mo - mn);
            m = mn;
        }
        float rden = 1.f / ssum;
        for (int base = beg; base < end; base += WAVE) {
            int e = base + lane;
            bool valid = (e < end);
            int sid = valid ? esrc[e] : 0;
            float wgt = 0.f;
            if (valid) {
                float v = as_[sid] + adn;
                v = (v > 0.f) ? v : 0.2f * v;
                wgt = __expf(v - m) * rden;
            }
            gather_accum_h(xw, q, g, min(WAVE, end - base), sid, wgt, acc);
        }
    }
    finish_store_q(acc, bias, out, n, q, g);
}

// ------------------------------- launch ------------------------------------

extern "C" void kernel_launch(void* const* d_in, const int* in_sizes, int n_in,
                              void* d_out, int out_size, void* d_ws, size_t ws_size,
                              hipStream_t stream) {
    const float* x   = (const float*)d_in[0];
    const int*   ei  = (const int*)d_in[1];
    const float* W1  = (const float*)d_in[2];
    const float* b1  = (const float*)d_in[3];
    const float* Wg1 = (const float*)d_in[4];
    const float* as1 = (const float*)d_in[5];
    const float* ad1 = (const float*)d_in[6];
    const float* bg1 = (const float*)d_in[7];
    const float* W2  = (const float*)d_in[8];
    const float* b2  = (const float*)d_in[9];
    const float* Wg2 = (const float*)d_in[10];
    const float* as2 = (const float*)d_in[11];
    const float* ad2 = (const float*)d_in[12];
    const float* bg2 = (const float*)d_in[13];
    const float* Wo  = (const float*)d_in[14];
    const float* bo  = (const float*)d_in[15];

    const int Nn = in_sizes[0] / 128;
    const int E  = in_sizes[1] / 2;
    const int Et = E + Nn;
    const int H  = 128;
    const int nbuck = (Nn + BK - 1) / BK;   // 196

    float* outH = (float*)d_out;
    float* outZ = outH + (size_t)Nn * H;

    char* p = (char*)d_ws;
    auto carve = [&](size_t bytes) {
        char* r = p;
        p += (bytes + 255) & ~(size_t)255;
        return r;
    };
    __half* bufA = (__half*)carve((size_t)Nn * H * sizeof(__half));  // xw (fp16)
    __half* Wt   = (__half*)carve((size_t)73728 * sizeof(__half));   // fp16 W^T x5
    float* alS   = (float*)carve((size_t)Nn * sizeof(float));
    float* alD   = (float*)carve((size_t)Nn * sizeof(float));
    float* inv   = (float*)carve((size_t)Nn * sizeof(float));
    int*   rowp  = (int*)carve((size_t)(Nn + 1) * sizeof(int));
    int*   esrc  = (int*)carve((size_t)Et * sizeof(int));
    int2*  ebuf  = (int2*)carve((size_t)Et * sizeof(int2));
    int*   bcnt  = (int*)carve((size_t)nbuck * sizeof(int));
    int*   bbase = (int*)carve((size_t)(nbuck + 1) * sizeof(int));
    int*   bcur  = (int*)carve((size_t)nbuck * sizeof(int));
    (void)ws_size; (void)n_in; (void)out_size;

    const int aggBlocks = (Nn * WAVE + 255) / 256;
    const int gemmB = (Nn + 127) / 128;           // 391
    const int scatB = (Et + CHUNK - 1) / CHUNK;   // 208

    // graph build (two-level bucket sort)
    k_zero_i32<<<1, 256, 0, stream>>>(bcnt, nbuck);
    k_bhist<<<104, 256, 0, stream>>>(ei, bcnt, E, Et, nbuck);
    k_bscan<<<1, 256, 0, stream>>>(bcnt, bbase, bcur, nbuck);
    k_bscatter<<<scatB, 256, 0, stream>>>(ei, bcur, ebuf, E, Et, nbuck);
    k_csr<<<nbuck, 256, 0, stream>>>(ebuf, bbase, rowp, inv, esrc, Nn, Et);
    k_wcvt<<<288, 256, 0, stream>>>(W1, Wg1, W2, Wg2, Wo, Wt);

    gemm_mfma<128, __half><<<gemmB, 256, 0, stream>>>(
        x, Wt, nullptr, bufA, nullptr, nullptr, nullptr, nullptr, Nn);
    k_gcn_agg<<<aggBlocks, 256, 0, stream>>>(bufA, rowp, esrc, inv, b1, outH, Nn);

    gemm_mfma<128, __half><<<gemmB, 256, 0, stream>>>(
        outH, Wt + 16384, nullptr, bufA, as1, ad1, alS, alD, Nn);
    k_gat_agg<<<aggBlocks, 256, 0, stream>>>(bufA, rowp, esrc, alS, alD, bg1, outH, Nn);

    gemm_mfma<128, __half><<<gemmB, 256, 0, stream>>>(
        outH, Wt + 32768, nullptr, bufA, nullptr, nullptr, nullptr, nullptr, Nn);
    k_gcn_agg<<<aggBlocks, 256, 0, stream>>>(bufA, rowp, esrc, inv, b2, outH, Nn);

    gemm_mfma<128, __half><<<gemmB, 256, 0, stream>>>(
        outH, Wt + 49152, nullptr, bufA, as2, ad2, alS, alD, Nn);
    k_gat_agg<<<aggBlocks, 256, 0, stream>>>(bufA, rowp, esrc, alS, alD, bg2, outH, Nn);

    gemm_mfma<64, float><<<gemmB, 256, 0, stream>>>(
        outH, Wt + 65536, bo, outZ, nullptr, nullptr, nullptr, nullptr, Nn);
}